// Round 22
// baseline (352.257 us; speedup 1.0000x reference)
//
#include <hip/hip_runtime.h>
#include <cstdint>

#define BB 256
#define TT 1000
#define DD 256
#define SS 10
#define HH 64
#define CC 100
// 2*log2(e): accumulate z2' = PRE*z so tanh(z) = 1 - 2/(exp2(z2')+1)
#define PRE 2.885390081777927f

typedef float f32x2 __attribute__((ext_vector_type(2)));
typedef float f32x4 __attribute__((ext_vector_type(4)));
typedef _Float16 f16x2 __attribute__((ext_vector_type(2)));
typedef _Float16 f16x8 __attribute__((ext_vector_type(8)));

__device__ __forceinline__ f32x2 lo2(f32x4 v) {
  return __builtin_shufflevector(v, v, 0, 1);
}
__device__ __forceinline__ f32x2 hi2(f32x4 v) {
  return __builtin_shufflevector(v, v, 2, 3);
}

// ---------------------------------------------------------------------------
// Kernel 1: input projection  xp[b,t,h] = PRE*(x . W_ih + b_ih + b_hh)
// R16-proven (~106 us). UNTOUCHED from R21.
// ---------------------------------------------------------------------------
__global__ __launch_bounds__(256) void proj_kernel(
    const float* __restrict__ x, const float* __restrict__ W_ih,
    const float* __restrict__ b_ih, const float* __restrict__ b_hh,
    float* __restrict__ xp) {
  __shared__ float As[64][68];
  __shared__ float Bs[64][68];
  const int s = blockIdx.y;
  const int r0 = blockIdx.x * 64;
  const int tid = threadIdx.x;
  const int ty = tid >> 4, tx = tid & 15;
  const int ty4 = ty * 4, tx4 = tx * 4;
  const int bswz = (tx & 7) << 2;
  f32x2 acc2[4][4];
#pragma unroll
  for (int i = 0; i < 4; ++i)
#pragma unroll
    for (int j = 0; j < 4; ++j) acc2[i][j] = (f32x2){0.f, 0.f};

  for (int kc = 0; kc < 4; ++kc) {
#pragma unroll
    for (int m = 0; m < 4; ++m) {
      int f = m * 256 + tid;
      int row = f >> 4, kq = f & 15;
      int r = r0 + row;
      int b = r / CC, c = r - b * CC;
      const float4 av = *(const float4*)(
          x + ((size_t)b * TT + s * CC + c) * DD + kc * 64 + kq * 4);
      *(float4*)&As[row][kq * 4] = av;
      const float4 wv = *(const float4*)(
          W_ih + ((size_t)s * HH + row) * DD + kc * 64 + kq * 4);
      *(float4*)&Bs[row][(kq * 4) ^ (((row >> 2) & 7) << 2)] = wv;
    }
    __syncthreads();
#pragma unroll 4
    for (int k = 0; k < 64; k += 4) {
      const int kx = k ^ bswz;
      f32x4 a[4], w[4];
#pragma unroll
      for (int i = 0; i < 4; ++i) a[i] = *(const f32x4*)&As[ty4 + i][k];
#pragma unroll
      for (int j = 0; j < 4; ++j) w[j] = *(const f32x4*)&Bs[tx4 + j][kx];
#pragma unroll
      for (int i = 0; i < 4; ++i)
#pragma unroll
        for (int j = 0; j < 4; ++j) {
          acc2[i][j] = __builtin_elementwise_fma(lo2(a[i]), lo2(w[j]), acc2[i][j]);
          acc2[i][j] = __builtin_elementwise_fma(hi2(a[i]), hi2(w[j]), acc2[i][j]);
        }
    }
    __syncthreads();
  }

  const float4 b1 = *(const float4*)(b_ih + s * HH + tx4);
  const float4 b2 = *(const float4*)(b_hh + s * HH + tx4);
#pragma unroll
  for (int i = 0; i < 4; ++i) {
    int r = r0 + ty4 + i;
    int b = r / CC, c = r - b * CC;
    float4 o;
    o.x = PRE * ((acc2[i][0].x + acc2[i][0].y) + b1.x + b2.x);
    o.y = PRE * ((acc2[i][1].x + acc2[i][1].y) + b1.y + b2.y);
    o.z = PRE * ((acc2[i][2].x + acc2[i][2].y) + b1.z + b2.z);
    o.w = PRE * ((acc2[i][3].x + acc2[i][3].y) + b1.w + b2.w);
    *(float4*)(xp + ((size_t)b * TT + s * CC + c) * HH + tx4) = o;
  }
}

// ---------------------------------------------------------------------------
// Kernel 2: recurrence + fused head, f16-LDS variant of the R13 structure.
// h stored in LDS as f16 (row = 64 halves = 128B): broadcast read is 8
// ds_read_b128 (was 16) and the W.h MAC uses v_dot2_f32_f16 (2 MAC/slot,
// f32 accumulate). W and fc_w packed to f16x2 per segment (off-chain).
// Everything else identical to the proven R13/R21 body: 4-deep xp ring,
// exp2-prescaled tanh, per-segment fused head, single wave per b.
// Precision: f16 h (2^-11) + contractive tanh map -> ~1e-3 extra error,
// threshold 1.95e-2, previous absmax 3.9e-3.
// ---------------------------------------------------------------------------
__global__ __launch_bounds__(64, 1) void rnn_kernel(
    const float* __restrict__ xp, const float* __restrict__ W_hh,
    const float* __restrict__ fc_w, const float* __restrict__ fc_b,
    float* __restrict__ y) {
  __shared__ _Float16 hist[CC][72];  // 72-half row = 144B (bank spread 4/row)
  const int b = blockIdx.x;
  const int lane = threadIdx.x;
  hist[CC - 1][lane] = (_Float16)0.f;  // h0 = 0, read via cp at s=0,c=0

  f16x2 Wh[32];
  float h = 0.f;
  for (int s = 0; s < SS; ++s) {
    const float* wr = W_hh + ((size_t)s * HH + lane) * HH;
#pragma unroll
    for (int j = 0; j < 16; ++j) {
      float4 v = *(const float4*)(wr + 4 * j);
      Wh[2 * j]     = (f16x2){(_Float16)(PRE * v.x), (_Float16)(PRE * v.y)};
      Wh[2 * j + 1] = (f16x2){(_Float16)(PRE * v.z), (_Float16)(PRE * v.w)};
    }
    const float* xps = xp + ((size_t)b * TT + s * CC) * HH + lane;

    float xq0 = xps[0 * HH];
    float xq1 = xps[1 * HH];
    float xq2 = xps[2 * HH];
    float xq3 = xps[3 * HH];

    for (int c4 = 0; c4 < 25; ++c4) {
#pragma unroll
      for (int u = 0; u < 4; ++u) {
        const int c = c4 * 4 + u;
        const int cp = (c == 0) ? CC - 1 : c - 1;
        const float xv = (u == 0) ? xq0 : (u == 1) ? xq1 : (u == 2) ? xq2 : xq3;
        const _Float16* hb = &hist[cp][0];
        f16x8 r[8];
#pragma unroll
        for (int j = 0; j < 8; ++j) r[j] = *(const f16x8*)(hb + 8 * j);
        float a0 = xv, a1 = 0.f, a2 = 0.f, a3 = 0.f;
#pragma unroll
        for (int j = 0; j < 8; ++j) {
          a0 = __builtin_amdgcn_fdot2(
              Wh[4 * j + 0], __builtin_shufflevector(r[j], r[j], 0, 1), a0, false);
          a1 = __builtin_amdgcn_fdot2(
              Wh[4 * j + 1], __builtin_shufflevector(r[j], r[j], 2, 3), a1, false);
          a2 = __builtin_amdgcn_fdot2(
              Wh[4 * j + 2], __builtin_shufflevector(r[j], r[j], 4, 5), a2, false);
          a3 = __builtin_amdgcn_fdot2(
              Wh[4 * j + 3], __builtin_shufflevector(r[j], r[j], 6, 7), a3, false);
        }
        const float z2 = (a0 + a1) + (a2 + a3);  // = PRE * z
        const float e = __builtin_amdgcn_exp2f(z2);
        h = 1.f - 2.f * __builtin_amdgcn_rcpf(e + 1.f);
        hist[c][lane] = (_Float16)h;  // ds_write_b16 (2 lanes/bank = free)
        if (c4 < 24) {
          const float xn = xps[(c + 4) * HH];
          if (u == 0) xq0 = xn;
          else if (u == 1) xq1 = xn;
          else if (u == 2) xq2 = xn;
          else xq3 = xn;
        }
      }
    }

    // fused head for this segment: lane l -> y[b, s*CC + l]
    const float fb = fc_b[s];
    const float* fw = fc_w + s * HH;  // wave-uniform
    f16x2 fwh[32];
#pragma unroll
    for (int j = 0; j < 16; ++j) {
      float4 v = *(const float4*)(fw + 4 * j);
      fwh[2 * j]     = (f16x2){(_Float16)v.x, (_Float16)v.y};
      fwh[2 * j + 1] = (f16x2){(_Float16)v.z, (_Float16)v.w};
    }
#pragma unroll
    for (int base = 0; base < CC; base += 64) {
      int l = base + lane;
      if (l < CC) {
        const _Float16* hl = &hist[l][0];
        f16x8 r[8];
#pragma unroll
        for (int j = 0; j < 8; ++j) r[j] = *(const f16x8*)(hl + 8 * j);
        float za = fb, zb = 0.f;
#pragma unroll
        for (int j = 0; j < 8; ++j) {
          za = __builtin_amdgcn_fdot2(
              fwh[4 * j + 0], __builtin_shufflevector(r[j], r[j], 0, 1), za, false);
          zb = __builtin_amdgcn_fdot2(
              fwh[4 * j + 1], __builtin_shufflevector(r[j], r[j], 2, 3), zb, false);
          za = __builtin_amdgcn_fdot2(
              fwh[4 * j + 2], __builtin_shufflevector(r[j], r[j], 4, 5), za, false);
          zb = __builtin_amdgcn_fdot2(
              fwh[4 * j + 3], __builtin_shufflevector(r[j], r[j], 6, 7), zb, false);
        }
        y[(size_t)b * TT + s * CC + l] =
            __builtin_amdgcn_rcpf(1.f + __expf(-(za + zb)));
      }
    }
  }
}

extern "C" void kernel_launch(void* const* d_in, const int* in_sizes, int n_in,
                              void* d_out, int out_size, void* d_ws,
                              size_t ws_size, hipStream_t stream) {
  const float* x    = (const float*)d_in[0];
  const float* W_ih = (const float*)d_in[1];
  const float* W_hh = (const float*)d_in[2];
  const float* b_ih = (const float*)d_in[3];
  const float* b_hh = (const float*)d_in[4];
  const float* fc_w = (const float*)d_in[5];
  const float* fc_b = (const float*)d_in[6];
  float* y  = (float*)d_out;
  float* xp = (float*)d_ws;  // [B][T][H] fp32 = 65.5 MB

  proj_kernel<<<dim3(400, 10), 256, 0, stream>>>(x, W_ih, b_ih, b_hh, xp);
  rnn_kernel<<<256, 64, 0, stream>>>(xp, W_hh, fc_w, fc_b, y);
}

// Round 23
// 314.048 us; speedup vs baseline: 1.1217x; 1.1217x over previous
//
#include <hip/hip_runtime.h>
#include <cstdint>

#define BB 256
#define TT 1000
#define DD 256
#define SS 10
#define HH 64
#define CC 100
// 2*log2(e): accumulate z2' = PRE*z so tanh(z) = 1 - 2/(exp2(z2')+1)
#define PRE 2.885390081777927f

typedef float f32x2 __attribute__((ext_vector_type(2)));
typedef float f32x4 __attribute__((ext_vector_type(4)));

__device__ __forceinline__ f32x2 lo2(f32x4 v) {
  return __builtin_shufflevector(v, v, 0, 1);
}
__device__ __forceinline__ f32x2 hi2(f32x4 v) {
  return __builtin_shufflevector(v, v, 2, 3);
}

// ---------------------------------------------------------------------------
// Kernel 1: input projection  xp[b,t,h] = PRE*(x . W_ih + b_ih + b_hh)
// R16-proven (~106 us): Bs XOR-swizzle (kills the 8-way read conflict
// present since R0) + pk_fma inner loop (halves FMA issue slots).
// ---------------------------------------------------------------------------
__global__ __launch_bounds__(256) void proj_kernel(
    const float* __restrict__ x, const float* __restrict__ W_ih,
    const float* __restrict__ b_ih, const float* __restrict__ b_hh,
    float* __restrict__ xp) {
  __shared__ float As[64][68];
  __shared__ float Bs[64][68];
  const int s = blockIdx.y;
  const int r0 = blockIdx.x * 64;
  const int tid = threadIdx.x;
  const int ty = tid >> 4, tx = tid & 15;
  const int ty4 = ty * 4, tx4 = tx * 4;
  const int bswz = (tx & 7) << 2;  // read-side col XOR (== ((row>>2)&7)<<2)
  f32x2 acc2[4][4];
#pragma unroll
  for (int i = 0; i < 4; ++i)
#pragma unroll
    for (int j = 0; j < 4; ++j) acc2[i][j] = (f32x2){0.f, 0.f};

  for (int kc = 0; kc < 4; ++kc) {
#pragma unroll
    for (int m = 0; m < 4; ++m) {
      int f = m * 256 + tid;
      int row = f >> 4, kq = f & 15;
      int r = r0 + row;
      int b = r / CC, c = r - b * CC;
      const float4 av = *(const float4*)(
          x + ((size_t)b * TT + s * CC + c) * DD + kc * 64 + kq * 4);
      *(float4*)&As[row][kq * 4] = av;
      const float4 wv = *(const float4*)(
          W_ih + ((size_t)s * HH + row) * DD + kc * 64 + kq * 4);
      *(float4*)&Bs[row][(kq * 4) ^ (((row >> 2) & 7) << 2)] = wv;
    }
    __syncthreads();
#pragma unroll 4
    for (int k = 0; k < 64; k += 4) {
      const int kx = k ^ bswz;
      f32x4 a[4], w[4];
#pragma unroll
      for (int i = 0; i < 4; ++i) a[i] = *(const f32x4*)&As[ty4 + i][k];
#pragma unroll
      for (int j = 0; j < 4; ++j) w[j] = *(const f32x4*)&Bs[tx4 + j][kx];
#pragma unroll
      for (int i = 0; i < 4; ++i)
#pragma unroll
        for (int j = 0; j < 4; ++j) {
          acc2[i][j] = __builtin_elementwise_fma(lo2(a[i]), lo2(w[j]), acc2[i][j]);
          acc2[i][j] = __builtin_elementwise_fma(hi2(a[i]), hi2(w[j]), acc2[i][j]);
        }
    }
    __syncthreads();
  }

  const float4 b1 = *(const float4*)(b_ih + s * HH + tx4);
  const float4 b2 = *(const float4*)(b_hh + s * HH + tx4);
#pragma unroll
  for (int i = 0; i < 4; ++i) {
    int r = r0 + ty4 + i;
    int b = r / CC, c = r - b * CC;
    float4 o;
    o.x = PRE * ((acc2[i][0].x + acc2[i][0].y) + b1.x + b2.x);
    o.y = PRE * ((acc2[i][1].x + acc2[i][1].y) + b1.y + b2.y);
    o.z = PRE * ((acc2[i][2].x + acc2[i][2].y) + b1.z + b2.z);
    o.w = PRE * ((acc2[i][3].x + acc2[i][3].y) + b1.w + b2.w);
    *(float4*)(xp + ((size_t)b * TT + s * CC + c) * HH + tx4) = o;
  }
}

// ---------------------------------------------------------------------------
// Kernel 2: recurrence + fused head (R13-proven, ~205 us). Single wave per
// b; 16 ds_read_b128 broadcast + 32 v_pk_fma_f32 per step; exp2-prescaled
// tanh; 4-deep xp ring; per-segment fused head.
// Measured-dead alternatives: readlane/bpermute broadcast (R3/R4), forced
// read clustering (R5), asm-scheduled counted waits (R8), 4-wave K-split
// (R11/R12), f16+fdot2 (R22: operand-repack slots > savings), and four
// proj-overlap topologies (R14/R15/R18/R20). This is the slot floor of the
// 1-wave/CU regime at its depressed (~740 MHz effective) clock.
// ---------------------------------------------------------------------------
__global__ __launch_bounds__(64, 1) void rnn_kernel(
    const float* __restrict__ xp, const float* __restrict__ W_hh,
    const float* __restrict__ fc_w, const float* __restrict__ fc_b,
    float* __restrict__ y) {
  __shared__ float hist[CC][68];
  const int b = blockIdx.x;
  const int lane = threadIdx.x;
  hist[CC - 1][lane] = 0.f;  // h0 = 0, read via cp at s=0,c=0

  f32x2 Wp[32];
  float h = 0.f;
  for (int s = 0; s < SS; ++s) {
    const float* wr = W_hh + ((size_t)s * HH + lane) * HH;
#pragma unroll
    for (int j = 0; j < 16; ++j) {
      float4 v = *(const float4*)(wr + 4 * j);
      Wp[2 * j]     = (f32x2){PRE * v.x, PRE * v.y};
      Wp[2 * j + 1] = (f32x2){PRE * v.z, PRE * v.w};
    }
    const float* xps = xp + ((size_t)b * TT + s * CC) * HH + lane;

    float xq0 = xps[0 * HH];
    float xq1 = xps[1 * HH];
    float xq2 = xps[2 * HH];
    float xq3 = xps[3 * HH];

    for (int c4 = 0; c4 < 25; ++c4) {
#pragma unroll
      for (int u = 0; u < 4; ++u) {
        const int c = c4 * 4 + u;
        const int cp = (c == 0) ? CC - 1 : c - 1;
        const float xv = (u == 0) ? xq0 : (u == 1) ? xq1 : (u == 2) ? xq2 : xq3;
        f32x2 acc0 = {xv, 0.f};
        f32x2 acc1 = {0.f, 0.f};
#pragma unroll
        for (int j4 = 0; j4 < 16; ++j4) {
          const f32x4 hv = *(const f32x4*)&hist[cp][j4 * 4];
          acc0 = __builtin_elementwise_fma(Wp[2 * j4], lo2(hv), acc0);
          acc1 = __builtin_elementwise_fma(Wp[2 * j4 + 1], hi2(hv), acc1);
        }
        const f32x2 t = acc0 + acc1;
        const float z2 = t.x + t.y;          // = PRE * z
        const float e = __builtin_amdgcn_exp2f(z2);
        h = 1.f - 2.f * __builtin_amdgcn_rcpf(e + 1.f);
        hist[c][lane] = h;
        if (c4 < 24) {
          const float xn = xps[(c + 4) * HH];
          if (u == 0) xq0 = xn;
          else if (u == 1) xq1 = xn;
          else if (u == 2) xq2 = xn;
          else xq3 = xn;
        }
      }
    }

    // fused head for this segment: lane l -> y[b, s*CC + l]
    const float fb = fc_b[s];
    const float* fw = fc_w + s * HH;  // wave-uniform
#pragma unroll
    for (int base = 0; base < CC; base += 64) {
      int l = base + lane;
      if (l < CC) {
        float z = fb;
#pragma unroll
        for (int i = 0; i < 64; i += 4) {
          const float4 hv = *(const float4*)&hist[l][i];
          z += hv.x * fw[i] + hv.y * fw[i + 1] + hv.z * fw[i + 2] +
               hv.w * fw[i + 3];
        }
        y[(size_t)b * TT + s * CC + l] =
            __builtin_amdgcn_rcpf(1.f + __expf(-z));
      }
    }
  }
}

extern "C" void kernel_launch(void* const* d_in, const int* in_sizes, int n_in,
                              void* d_out, int out_size, void* d_ws,
                              size_t ws_size, hipStream_t stream) {
  const float* x    = (const float*)d_in[0];
  const float* W_ih = (const float*)d_in[1];
  const float* W_hh = (const float*)d_in[2];
  const float* b_ih = (const float*)d_in[3];
  const float* b_hh = (const float*)d_in[4];
  const float* fc_w = (const float*)d_in[5];
  const float* fc_b = (const float*)d_in[6];
  float* y  = (float*)d_out;
  float* xp = (float*)d_ws;  // [B][T][H] fp32 = 65.5 MB

  proj_kernel<<<dim3(400, 10), 256, 0, stream>>>(x, W_ih, b_ih, b_hh, xp);
  rnn_kernel<<<256, 64, 0, stream>>>(xp, W_hh, fc_w, fc_b, y);
}